// Round 2
// baseline (1753.193 us; speedup 1.0000x reference)
//
#include <hip/hip_runtime.h>

typedef unsigned short u16;
typedef unsigned int u32;
typedef __bf16 v8bf __attribute__((ext_vector_type(8)));
typedef float v4f __attribute__((ext_vector_type(4)));

#define ROWS_PB 32
#define TOK 96          // 3*ROWS_PB tokens per block
#define XS 72           // sX/sATT row stride (bf16 elems), +8 pad
#define QS 194          // sQKV row stride (bf16 elems): 192 cols + 2 pad (odd dword stride)
#define PS 68           // sPRE row stride (bf16 elems)
#define WS_L 20480      // packed bf16 weight elems per layer

struct Params {
  const float *h0, *h1, *h2;
  const float *m0, *m1, *m2;
  const float *relw, *relb;
  const float *b_qkv[2], *b_o[2], *b_f[2];
  const float *n1g[2], *n1b[2], *n2g[2], *n2b[2];
  const u16* ws;
  float* out;
};

__device__ __forceinline__ float bf2f(u16 u){ return __uint_as_float(((u32)u) << 16); }
__device__ __forceinline__ u16 f2bf(float f){
  u32 u = __float_as_uint(f);
  u += 0x7fffu + ((u >> 16) & 1u);
  return (u16)(u >> 16);
}

union Frag { uint2 u2[2]; uint4 u4; v8bf v; u16 s[8]; };
union V16  { uint2 u2[4]; uint4 u4[2]; u16 s[16]; };

__device__ __forceinline__ float wredsum(float v){
#pragma unroll
  for (int m = 32; m >= 1; m >>= 1) v += __shfl_xor(v, m, 64);
  return v;
}

// Pack weights as bf16 B-operand fragments for v_mfma_f32_16x16x32_bf16:
// lane l, elem e: n = nt*16 + (l&15); k = kk*32 + 4*(l>>4) + (e&3) + (e>>2)*16
__global__ __launch_bounds__(256, 2)
void prep_w(const float* wq0, const float* wo0, const float* wf0,
            const float* wq1, const float* wo1, const float* wf1, u16* ws){
  int idx = blockIdx.x * 256 + threadIdx.x;
  if (idx >= 2 * WS_L) return;
  int l = idx / WS_L, rem = idx % WS_L;
  const float* W; int loc;
  if (rem < 12288)      { W = l ? wq1 : wq0; loc = rem; }          // w_qkv (192x64): 12 nt * 2 kk * 512
  else if (rem < 16384) { W = l ? wo1 : wo0; loc = rem - 12288; }  // w_o (64x64): 4 nt * 2 kk * 512
  else                  { W = l ? wf1 : wf0; loc = rem - 16384; }  // ffn_w (64x64)
  int e = loc & 7, lane = (loc >> 3) & 63, fk = loc >> 9;
  int kk = fk & 1, nt = fk >> 1;
  int k = kk * 32 + 4 * (lane >> 4) + (e & 3) + (e >> 2) * 16;
  int n = nt * 16 + (lane & 15);
  ws[idx] = f2bf(W[n * 64 + k]);
}

__device__ __forceinline__ v8bf ldA(const u16* ap){
  Frag f;
  f.u2[0] = *(const uint2*)(ap);
  f.u2[1] = *(const uint2*)(ap + 16);
  return f.v;
}
__device__ __forceinline__ void ld16(V16& o, const u16* p){
#pragma unroll
  for (int i = 0; i < 4; ++i) o.u2[i] = *(const uint2*)(p + 4 * i);
}

__global__ __launch_bounds__(256, 2)
void inter_encoder(Params p){
  __shared__ u16  sX[TOK * XS];
  __shared__ u16  sQKV[TOK * QS];   // aliased as sPRE ([TOK][PS] bf16) after attention
  __shared__ u16  sATT[TOK * XS];
  __shared__ float sRel[TOK];

  const int tid  = threadIdx.x;
  const int lane = tid & 63, wv = tid >> 6;
  const int n15  = tid & 15, g  = (tid >> 4) & 3;
  const long long rowBase = (long long)blockIdx.x * ROWS_PB;
  const long long tokBase = rowBase * 3;

  // ---- phase 0: stage X (bf16), compute rel per token ----
  {
    const float* hs0 = p.h0; const float* hs1 = p.h1; const float* hs2 = p.h2;
#pragma unroll
    for (int it = 0; it < TOK * 64 / 256; ++it){
      int idx = it * 256 + tid;
      int t = idx >> 6, c = idx & 63;
      int r = t / 3, m = t - 3 * r;
      const float* hp = (m == 0) ? hs0 : (m == 1) ? hs1 : hs2;
      sX[t * XS + c] = f2bf(hp[(rowBase + r) * 64 + c]);
    }
    if (tid < TOK){
      int t = tid, r = t / 3, m = t - 3 * r;
      const float* mf = (m == 0) ? p.m0 : (m == 1) ? p.m1 : p.m2;
      float a0 = mf[(rowBase + r) * 2 + 0], a1 = mf[(rowBase + r) * 2 + 1];
      float z = a0 * p.relw[0] + a1 * p.relw[1] + p.relb[0];
      sRel[t] = 1.f / (1.f + __expf(-z));
    }
  }
  __syncthreads();

  u16* sPRE = sQKV;

  for (int l = 0; l < 2; ++l){
    const u16* wsl = p.ws + l * WS_L;

    // B-frags for qkv GEMM: wave wv owns n-tiles {3wv, 3wv+1, 3wv+2}
    Frag bq[3][2];
#pragma unroll
    for (int j = 0; j < 3; ++j)
#pragma unroll
      for (int kk = 0; kk < 2; ++kk)
        bq[j][kk].u4 = *(const uint4*)(wsl + (((3 * wv + j) * 2 + kk) * 64 + lane) * 8);
    float biasq[3];
#pragma unroll
    for (int j = 0; j < 3; ++j) biasq[j] = p.b_qkv[l][16 * (3 * wv + j) + n15];

    // ---- GEMM1: QKV[t][j] = sum_k X[t][k]*Wqkv[j][k] + b ----
#pragma unroll
    for (int mt = 0; mt < 6; ++mt){
      const u16* ap = sX + (16 * mt + n15) * XS + 4 * g;
      v8bf a0 = ldA(ap), a1 = ldA(ap + 32);
#pragma unroll
      for (int j = 0; j < 3; ++j){
        v4f acc = {biasq[j], biasq[j], biasq[j], biasq[j]};
        acc = __builtin_amdgcn_mfma_f32_16x16x32_bf16(a0, bq[j][0].v, acc, 0, 0, 0);
        acc = __builtin_amdgcn_mfma_f32_16x16x32_bf16(a1, bq[j][1].v, acc, 0, 0, 0);
        int jcol = 16 * (3 * wv + j) + n15;
        int t0 = 16 * mt + 4 * g;
#pragma unroll
        for (int i = 0; i < 4; ++i)
          sQKV[(t0 + i) * QS + jcol] = f2bf(acc[i]);
      }
    }
    __syncthreads();

    // ---- attention: thread (r,h), 128 threads active ----
    if (tid < 128){
      int r = tid >> 2, h = tid & 3;
      const u16* base = sQKV + (3 * r) * QS + 16 * h;
      float qf[3][16], kf[3][16];
#pragma unroll
      for (int t = 0; t < 3; ++t){
        V16 a, b;
        ld16(a, base + t * QS);        // q
        ld16(b, base + t * QS + 64);   // k
#pragma unroll
        for (int d = 0; d < 16; ++d){ qf[t][d] = bf2f(a.s[d]); kf[t][d] = bf2f(b.s[d]); }
      }
      float s[3][3];
#pragma unroll
      for (int t1 = 0; t1 < 3; ++t1)
#pragma unroll
        for (int t2 = 0; t2 < 3; ++t2){
          float a = 0.f;
#pragma unroll
          for (int d = 0; d < 16; ++d) a += qf[t1][d] * kf[t2][d];
          s[t1][t2] = a * 0.25f;
        }
      float aw[3][3];
#pragma unroll
      for (int t1 = 0; t1 < 3; ++t1){
        float mx = fmaxf(fmaxf(s[t1][0], s[t1][1]), s[t1][2]);
        float e0 = __expf(s[t1][0] - mx), e1 = __expf(s[t1][1] - mx), e2 = __expf(s[t1][2] - mx);
        float inv = 1.f / (e0 + e1 + e2);
        aw[t1][0] = e0 * inv; aw[t1][1] = e1 * inv; aw[t1][2] = e2 * inv;
      }
      float vf[3][16];
#pragma unroll
      for (int t = 0; t < 3; ++t){
        V16 a; ld16(a, base + t * QS + 128);
#pragma unroll
        for (int d = 0; d < 16; ++d) vf[t][d] = bf2f(a.s[d]);
      }
#pragma unroll
      for (int t1 = 0; t1 < 3; ++t1){
        V16 o;
#pragma unroll
        for (int d = 0; d < 16; ++d){
          float ov = aw[t1][0] * vf[0][d] + aw[t1][1] * vf[1][d] + aw[t1][2] * vf[2][d];
          o.s[d] = f2bf(ov);
        }
        u16* op = sATT + (3 * r + t1) * XS + 16 * h;
        *(uint4*)(op)     = o.u4[0];
        *(uint4*)(op + 8) = o.u4[1];
      }
    }
    __syncthreads();

    // B-frags for o-proj / ffn (loaded late to cut attention-phase VGPR pressure)
    Frag bo[2], bf[2];
#pragma unroll
    for (int kk = 0; kk < 2; ++kk){
      bo[kk].u4 = *(const uint4*)(wsl + 12288 + ((wv * 2 + kk) * 64 + lane) * 8);
      bf[kk].u4 = *(const uint4*)(wsl + 16384 + ((wv * 2 + kk) * 64 + lane) * 8);
    }
    float biaso = p.b_o[l][16 * wv + n15];
    float biasf = p.b_f[l][16 * wv + n15];

    // ---- GEMM2: PRE = (ATT*Wo^T + b_o)*rel + X ----
#pragma unroll
    for (int mt = 0; mt < 6; ++mt){
      const u16* ap = sATT + (16 * mt + n15) * XS + 4 * g;
      v8bf a0 = ldA(ap), a1 = ldA(ap + 32);
      v4f acc = {biaso, biaso, biaso, biaso};
      acc = __builtin_amdgcn_mfma_f32_16x16x32_bf16(a0, bo[0].v, acc, 0, 0, 0);
      acc = __builtin_amdgcn_mfma_f32_16x16x32_bf16(a1, bo[1].v, acc, 0, 0, 0);
      int n = 16 * wv + n15, t0 = 16 * mt + 4 * g;
#pragma unroll
      for (int i = 0; i < 4; ++i){
        int t = t0 + i;
        float val = acc[i] * sRel[t] + bf2f(sX[t * XS + n]);
        sPRE[t * PS + n] = f2bf(val);
      }
    }
    __syncthreads();

    // ---- LN1 -> X ----
    {
      float gc = p.n1g[l][lane], bc = p.n1b[l][lane];
#pragma unroll
      for (int it = 0; it < TOK / 4; ++it){
        int t = wv * (TOK / 4) + it;
        float v = bf2f(sPRE[t * PS + lane]);
        float mu = wredsum(v) * (1.f / 64.f);
        float d = v - mu;
        float var = wredsum(d * d) * (1.f / 64.f);
        float y = d * rsqrtf(var + 1e-5f) * gc + bc;
        sX[t * XS + lane] = f2bf(y);
      }
    }
    __syncthreads();

    // ---- GEMM3: PRE = X + relu(X*Wf^T + b_f) ----
#pragma unroll
    for (int mt = 0; mt < 6; ++mt){
      const u16* ap = sX + (16 * mt + n15) * XS + 4 * g;
      v8bf a0 = ldA(ap), a1 = ldA(ap + 32);
      v4f acc = {biasf, biasf, biasf, biasf};
      acc = __builtin_amdgcn_mfma_f32_16x16x32_bf16(a0, bf[0].v, acc, 0, 0, 0);
      acc = __builtin_amdgcn_mfma_f32_16x16x32_bf16(a1, bf[1].v, acc, 0, 0, 0);
      int n = 16 * wv + n15, t0 = 16 * mt + 4 * g;
#pragma unroll
      for (int i = 0; i < 4; ++i){
        int t = t0 + i;
        float val = bf2f(sX[t * XS + n]) + fmaxf(acc[i], 0.f);
        sPRE[t * PS + n] = f2bf(val);
      }
    }
    __syncthreads();

    // ---- LN2 -> X (layer 0) or d_out (layer 1) ----
    {
      float gc = p.n2g[l][lane], bc = p.n2b[l][lane];
#pragma unroll
      for (int it = 0; it < TOK / 4; ++it){
        int t = wv * (TOK / 4) + it;
        float v = bf2f(sPRE[t * PS + lane]);
        float mu = wredsum(v) * (1.f / 64.f);
        float d = v - mu;
        float var = wredsum(d * d) * (1.f / 64.f);
        float y = d * rsqrtf(var + 1e-5f) * gc + bc;
        if (l == 0) sX[t * XS + lane] = f2bf(y);
        else        p.out[(tokBase + t) * 64 + lane] = y;
      }
    }
    __syncthreads();
  }
}

extern "C" void kernel_launch(void* const* d_in, const int* in_sizes, int n_in,
                              void* d_out, int out_size, void* d_ws, size_t ws_size,
                              hipStream_t stream){
  const float* const* in = (const float* const*)d_in;
  u16* ws = (u16*)d_ws;

  // pack bf16 weight fragments (idempotent, deterministic)
  prep_w<<<(2 * WS_L + 255) / 256, 256, 0, stream>>>(
      in[8], in[10], in[12], in[18], in[20], in[22], ws);

  Params p;
  p.h0 = in[0]; p.h1 = in[1]; p.h2 = in[2];
  p.m0 = in[3]; p.m1 = in[4]; p.m2 = in[5];
  p.relw = in[6]; p.relb = in[7];
  for (int l = 0; l < 2; ++l){
    int b = 8 + 10 * l;
    p.b_qkv[l] = in[b + 1];
    p.b_o[l]   = in[b + 3];
    p.b_f[l]   = in[b + 5];
    p.n1g[l]   = in[b + 6]; p.n1b[l] = in[b + 7];
    p.n2g[l]   = in[b + 8]; p.n2b[l] = in[b + 9];
  }
  p.ws = ws;
  p.out = (float*)d_out;

  const int nblk = 524288 / ROWS_PB;  // 16384
  inter_encoder<<<nblk, 256, 0, stream>>>(p);
}

// Round 3
// 476.200 us; speedup vs baseline: 3.6816x; 3.6816x over previous
//
#include <hip/hip_runtime.h>

typedef unsigned short u16;
typedef unsigned int u32;
typedef _Float16 h16;
typedef h16 h2v __attribute__((ext_vector_type(2)));
typedef h16 v8h __attribute__((ext_vector_type(8)));
typedef float v4f __attribute__((ext_vector_type(4)));

#define ROWS_PB 16
#define TOK 48          // 3*ROWS_PB tokens per block
#define XS 76           // sX row stride (f16 elems): 64 + 12 pad, 8B-aligned rows, uniform banks
#define QS 196          // sQKV row stride (f16 elems): 192 + 4 pad, 8B-aligned rows
#define WS_L 20480      // packed f16 weight elems per layer

struct Params {
  const float *h0, *h1, *h2;
  const float *m0, *m1, *m2;
  const float *relw, *relb;
  const float *b_qkv[2], *b_o[2], *b_f[2];
  const float *n1g[2], *n1b[2], *n2g[2], *n2b[2];
  const u16* ws;
  float* out;
};

__device__ __forceinline__ u16 f2h(float f){ union{h16 h; u16 u;} c; c.h = (h16)f; return c.u; }
__device__ __forceinline__ float h2f(u16 u){ union{u16 u2; h16 h;} c; c.u2 = u; return (float)c.h; }

union Frag { uint2 u2[2]; uint4 u4; v8h v; };
union V16h { uint2 u2[4]; h2v h[8]; h16 s[16]; };

#if __has_builtin(__builtin_amdgcn_fdot2)
#define FDOT2(a,b,c) __builtin_amdgcn_fdot2((a),(b),(c),false)
#else
#define FDOT2(a,b,c) ((float)(a)[0]*(float)(b)[0] + (float)(a)[1]*(float)(b)[1] + (c))
#endif

// Pack weights as f16 B-operand fragments for v_mfma_f32_16x16x32_f16:
// lane l, elem e: n = nt*16 + (l&15); k = kk*32 + 4*(l>>4) + (e&3) + 16*(e>>2)
__global__ __launch_bounds__(256, 2)
void prep_w(const float* wq0, const float* wo0, const float* wf0,
            const float* wq1, const float* wo1, const float* wf1, u16* ws){
  int idx = blockIdx.x * 256 + threadIdx.x;
  if (idx >= 2 * WS_L) return;
  int l = idx / WS_L, rem = idx % WS_L;
  const float* W; int loc;
  if (rem < 12288)      { W = l ? wq1 : wq0; loc = rem; }          // w_qkv (192x64)
  else if (rem < 16384) { W = l ? wo1 : wo0; loc = rem - 12288; }  // w_o (64x64)
  else                  { W = l ? wf1 : wf0; loc = rem - 16384; }  // ffn_w (64x64)
  int e = loc & 7, lane = (loc >> 3) & 63, fk = loc >> 9;
  int kk = fk & 1, nt = fk >> 1;
  int k = kk * 32 + 4 * (lane >> 4) + (e & 3) + (e >> 2) * 16;
  int n = nt * 16 + (lane & 15);
  ws[idx] = f2h(W[n * 64 + k]);
}

__device__ __forceinline__ v8h ldA(const u16* ap){
  Frag f;
  f.u2[0] = *(const uint2*)(ap);
  f.u2[1] = *(const uint2*)(ap + 16);
  return f.v;
}
__device__ __forceinline__ void ld16(V16h& o, const u16* p){
#pragma unroll
  for (int i = 0; i < 4; ++i) o.u2[i] = *(const uint2*)(p + 4 * i);
}

__device__ __forceinline__ float red16(float v){
  v += __shfl_xor(v, 1, 64);
  v += __shfl_xor(v, 2, 64);
  v += __shfl_xor(v, 4, 64);
  v += __shfl_xor(v, 8, 64);
  return v;
}

__global__ __launch_bounds__(192, 4)
void inter_encoder(Params p){
  __shared__ u16  sX[TOK * XS];
  __shared__ u16  sQKV[TOK * QS];   // cols 0..63 re-used as ATT after attention
  __shared__ float sRel[TOK];

  const int tid  = threadIdx.x;
  const int lane = tid & 63, wv = tid >> 6;     // wv in 0..2
  const int n15  = lane & 15, g = lane >> 4;    // g in 0..3
  const long long rowBase = (long long)blockIdx.x * ROWS_PB;

  // ---- stage X (f16) via float4, compute rel per token ----
#pragma unroll
  for (int it = 0; it < 4; ++it){
    int idx = it * 192 + tid;              // 768 float4 slots = [48][16]
    int t = idx >> 4, c4 = (idx & 15) * 4;
    int r = t / 3, m = t - 3 * r;
    const float* hp = (m == 0) ? p.h0 : (m == 1) ? p.h1 : p.h2;
    float4 vv = *(const float4*)(hp + (rowBase + r) * 64 + c4);
    u32 lo = (u32)f2h(vv.x) | ((u32)f2h(vv.y) << 16);
    u32 hi = (u32)f2h(vv.z) | ((u32)f2h(vv.w) << 16);
    *(uint2*)(sX + t * XS + c4) = make_uint2(lo, hi);
  }
  if (tid < TOK){
    int t = tid, r = t / 3, m = t - 3 * r;
    const float* mf = (m == 0) ? p.m0 : (m == 1) ? p.m1 : p.m2;
    float a0 = mf[(rowBase + r) * 2 + 0], a1 = mf[(rowBase + r) * 2 + 1];
    float z = a0 * p.relw[0] + a1 * p.relw[1] + p.relb[0];
    sRel[t] = 1.f / (1.f + __expf(-z));
  }
  __syncthreads();

  for (int l = 0; l < 2; ++l){
    const u16* wsl = p.ws + l * WS_L;

    // ---- GEMM1 (n-split): wave wv owns n-tiles 4wv..4wv+3 ----
    Frag bq[4][2];
    float biasq[4];
#pragma unroll
    for (int j = 0; j < 4; ++j){
      int nt = 4 * wv + j;
#pragma unroll
      for (int kk = 0; kk < 2; ++kk)
        bq[j][kk].u4 = *(const uint4*)(wsl + ((nt * 2 + kk) * 64 + lane) * 8);
      biasq[j] = p.b_qkv[l][16 * nt + n15];
    }
#pragma unroll
    for (int mt = 0; mt < 3; ++mt){
      const u16* ap = sX + (16 * mt + n15) * XS + 4 * g;
      v8h a0 = ldA(ap), a1 = ldA(ap + 32);
#pragma unroll
      for (int j = 0; j < 4; ++j){
        v4f acc = {biasq[j], biasq[j], biasq[j], biasq[j]};
        acc = __builtin_amdgcn_mfma_f32_16x16x32_f16(a0, bq[j][0].v, acc, 0, 0, 0);
        acc = __builtin_amdgcn_mfma_f32_16x16x32_f16(a1, bq[j][1].v, acc, 0, 0, 0);
        int jcol = 16 * (4 * wv + j) + n15, t0 = 16 * mt + 4 * g;
#pragma unroll
        for (int i = 0; i < 4; ++i)
          sQKV[(t0 + i) * QS + jcol] = f2h(acc[i]);
      }
    }
    __syncthreads();

    // ---- attention: wave = query token t1, lane = (r, h) ----
    {
      const int t1 = wv, r = lane >> 2, h = lane & 3;
      const u16* base = sQKV + (3 * r) * QS + 16 * h;
      V16h q, k0, k1, k2;
      ld16(q,  base + t1 * QS);
      ld16(k0, base + 64);
      ld16(k1, base + QS + 64);
      ld16(k2, base + 2 * QS + 64);
      float s0 = 0.f, s1 = 0.f, s2 = 0.f;
#pragma unroll
      for (int pp = 0; pp < 8; ++pp){
        s0 = FDOT2(q.h[pp], k0.h[pp], s0);
        s1 = FDOT2(q.h[pp], k1.h[pp], s1);
        s2 = FDOT2(q.h[pp], k2.h[pp], s2);
      }
      s0 *= 0.25f; s1 *= 0.25f; s2 *= 0.25f;
      float mx = fmaxf(fmaxf(s0, s1), s2);
      float e0 = __expf(s0 - mx), e1 = __expf(s1 - mx), e2 = __expf(s2 - mx);
      float inv = 1.f / (e0 + e1 + e2);
      h16 w0 = (h16)(e0 * inv), w1 = (h16)(e1 * inv), w2 = (h16)(e2 * inv);
      h2v aw0 = {w0, w0}, aw1 = {w1, w1}, aw2 = {w2, w2};
      V16h v0, v1, v2, o;
      ld16(v0, base + 128);
      ld16(v1, base + QS + 128);
      ld16(v2, base + 2 * QS + 128);
#pragma unroll
      for (int pp = 0; pp < 8; ++pp)
        o.h[pp] = aw0 * v0.h[pp] + aw1 * v1.h[pp] + aw2 * v2.h[pp];
      // write ATT into the (already-consumed) Q region of this thread's own token
      u16* op = sQKV + (3 * r + t1) * QS + 16 * h;
#pragma unroll
      for (int pp = 0; pp < 4; ++pp) *(uint2*)(op + 4 * pp) = o.u2[pp];
    }
    __syncthreads();

    // ---- GEMM2 + LN1 (m-split: wave wv owns tokens 16wv..16wv+15) ----
    Frag bo[4][2];
    float biaso[4], g1v[4], b1v[4];
#pragma unroll
    for (int j = 0; j < 4; ++j){
#pragma unroll
      for (int kk = 0; kk < 2; ++kk)
        bo[j][kk].u4 = *(const uint4*)(wsl + 12288 + ((j * 2 + kk) * 64 + lane) * 8);
      biaso[j] = p.b_o[l][16 * j + n15];
      g1v[j] = p.n1g[l][16 * j + n15];
      b1v[j] = p.n1b[l][16 * j + n15];
    }
    {
      const u16* ap = sQKV + (16 * wv + n15) * QS + 4 * g;  // ATT rows, cols 0..63
      v8h a0 = ldA(ap), a1 = ldA(ap + 32);
      v4f acc[4];
#pragma unroll
      for (int j = 0; j < 4; ++j){
        acc[j] = (v4f){biaso[j], biaso[j], biaso[j], biaso[j]};
        acc[j] = __builtin_amdgcn_mfma_f32_16x16x32_f16(a0, bo[j][0].v, acc[j], 0, 0, 0);
        acc[j] = __builtin_amdgcn_mfma_f32_16x16x32_f16(a1, bo[j][1].v, acc[j], 0, 0, 0);
      }
#pragma unroll
      for (int i = 0; i < 4; ++i){
        int t = 16 * wv + 4 * g + i;
        float relt = sRel[t];
        float val[4], psum = 0.f;
#pragma unroll
        for (int j = 0; j < 4; ++j){
          val[j] = acc[j][i] * relt + h2f(sX[t * XS + 16 * j + n15]);
          psum += val[j];
        }
        float mu = red16(psum) * (1.f / 64.f);
        float dv[4], vs = 0.f;
#pragma unroll
        for (int j = 0; j < 4; ++j){ dv[j] = val[j] - mu; vs += dv[j] * dv[j]; }
        float rs = rsqrtf(red16(vs) * (1.f / 64.f) + 1e-5f);
#pragma unroll
        for (int j = 0; j < 4; ++j)
          sX[t * XS + 16 * j + n15] = f2h(dv[j] * rs * g1v[j] + b1v[j]);
      }
    }

    // ---- GEMM3 + LN2 (same wave ownership; no barrier needed in between) ----
    Frag bf[4][2];
    float biasf[4], g2v[4], b2v[4];
#pragma unroll
    for (int j = 0; j < 4; ++j){
#pragma unroll
      for (int kk = 0; kk < 2; ++kk)
        bf[j][kk].u4 = *(const uint4*)(wsl + 16384 + ((j * 2 + kk) * 64 + lane) * 8);
      biasf[j] = p.b_f[l][16 * j + n15];
      g2v[j] = p.n2g[l][16 * j + n15];
      b2v[j] = p.n2b[l][16 * j + n15];
    }
    {
      const u16* ap = sX + (16 * wv + n15) * XS + 4 * g;
      v8h a0 = ldA(ap), a1 = ldA(ap + 32);
      v4f acc[4];
#pragma unroll
      for (int j = 0; j < 4; ++j){
        acc[j] = (v4f){biasf[j], biasf[j], biasf[j], biasf[j]};
        acc[j] = __builtin_amdgcn_mfma_f32_16x16x32_f16(a0, bf[j][0].v, acc[j], 0, 0, 0);
        acc[j] = __builtin_amdgcn_mfma_f32_16x16x32_f16(a1, bf[j][1].v, acc[j], 0, 0, 0);
      }
#pragma unroll
      for (int i = 0; i < 4; ++i){
        int t = 16 * wv + 4 * g + i;
        float val[4], psum = 0.f;
#pragma unroll
        for (int j = 0; j < 4; ++j){
          val[j] = h2f(sX[t * XS + 16 * j + n15]) + fmaxf(acc[j][i], 0.f);
          psum += val[j];
        }
        float mu = red16(psum) * (1.f / 64.f);
        float dv[4], vs = 0.f;
#pragma unroll
        for (int j = 0; j < 4; ++j){ dv[j] = val[j] - mu; vs += dv[j] * dv[j]; }
        float rs = rsqrtf(red16(vs) * (1.f / 64.f) + 1e-5f);
#pragma unroll
        for (int j = 0; j < 4; ++j){
          float y = dv[j] * rs * g2v[j] + b2v[j];
          if (l == 0) sX[t * XS + 16 * j + n15] = f2h(y);
          else        p.out[(rowBase * 3 + t) * 64 + 16 * j + n15] = y;
        }
      }
    }
    __syncthreads();
  }
}

extern "C" void kernel_launch(void* const* d_in, const int* in_sizes, int n_in,
                              void* d_out, int out_size, void* d_ws, size_t ws_size,
                              hipStream_t stream){
  const float* const* in = (const float* const*)d_in;
  u16* ws = (u16*)d_ws;

  prep_w<<<(2 * WS_L + 255) / 256, 256, 0, stream>>>(
      in[8], in[10], in[12], in[18], in[20], in[22], ws);

  Params p;
  p.h0 = in[0]; p.h1 = in[1]; p.h2 = in[2];
  p.m0 = in[3]; p.m1 = in[4]; p.m2 = in[5];
  p.relw = in[6]; p.relb = in[7];
  for (int l = 0; l < 2; ++l){
    int b = 8 + 10 * l;
    p.b_qkv[l] = in[b + 1];
    p.b_o[l]   = in[b + 3];
    p.b_f[l]   = in[b + 5];
    p.n1g[l]   = in[b + 6]; p.n1b[l] = in[b + 7];
    p.n2g[l]   = in[b + 8]; p.n2b[l] = in[b + 9];
  }
  p.ws = ws;
  p.out = (float*)d_out;

  const int nblk = 524288 / ROWS_PB;  // 32768
  inter_encoder<<<nblk, 192, 0, stream>>>(p);
}

// Round 6
// 464.940 us; speedup vs baseline: 3.7708x; 1.0242x over previous
//
#include <hip/hip_runtime.h>

typedef unsigned short u16;
typedef unsigned int u32;
typedef _Float16 h16;
typedef h16 h2v __attribute__((ext_vector_type(2)));
typedef h16 v8h __attribute__((ext_vector_type(8)));
typedef float v4f __attribute__((ext_vector_type(4)));

#define ROWS_PB 16
#define TOK 48          // 3*ROWS_PB tokens per block
#define XS 76           // sX row stride (f16 elems)
#define QS 196          // sQKV row stride (f16 elems): 192 + 4 pad
#define WS_L 20480      // packed f16 weight elems per layer

struct Params {
  const float *h0, *h1, *h2;
  const float *m0, *m1, *m2;
  const float *relw, *relb;
  const float *b_qkv[2], *b_o[2], *b_f[2];
  const float *n1g[2], *n1b[2], *n2g[2], *n2b[2];
  const u16* ws;
  float* out;
};

__device__ __forceinline__ u16 f2h(float f){ union{h16 h; u16 u;} c; c.h = (h16)f; return c.u; }
__device__ __forceinline__ float h2f(u16 u){ union{u16 u2; h16 h;} c; c.u2 = u; return (float)c.h; }

union Frag { uint2 u2[2]; uint4 u4; v8h v; };
union V16h { uint2 u2[4]; h2v h[8]; h16 s[16]; };

#if __has_builtin(__builtin_amdgcn_fdot2)
#define FDOT2(a,b,c) __builtin_amdgcn_fdot2((a),(b),(c),false)
#else
#define FDOT2(a,b,c) ((float)(a)[0]*(float)(b)[0] + (float)(a)[1]*(float)(b)[1] + (c))
#endif

// Pack weights as f16 fragments (A and B maps are identical):
// lane l, elem e: m/n = tile*16 + (l&15); k = kk*32 + 4*(l>>4) + (e&3) + 16*(e>>2)
__global__ __launch_bounds__(256, 2)
void prep_w(const float* wq0, const float* wo0, const float* wf0,
            const float* wq1, const float* wo1, const float* wf1, u16* ws){
  int idx = blockIdx.x * 256 + threadIdx.x;
  if (idx >= 2 * WS_L) return;
  int l = idx / WS_L, rem = idx % WS_L;
  const float* W; int loc;
  if (rem < 12288)      { W = l ? wq1 : wq0; loc = rem; }          // w_qkv (192x64)
  else if (rem < 16384) { W = l ? wo1 : wo0; loc = rem - 12288; }  // w_o (64x64)
  else                  { W = l ? wf1 : wf0; loc = rem - 16384; }  // ffn_w (64x64)
  int e = loc & 7, lane = (loc >> 3) & 63, fk = loc >> 9;
  int kk = fk & 1, nt = fk >> 1;
  int k = kk * 32 + 4 * (lane >> 4) + (e & 3) + (e >> 2) * 16;
  int n = nt * 16 + (lane & 15);
  ws[idx] = f2h(W[n * 64 + k]);
}

__device__ __forceinline__ v8h ldA(const u16* ap){
  Frag f;
  f.u2[0] = *(const uint2*)(ap);
  f.u2[1] = *(const uint2*)(ap + 16);
  return f.v;
}
__device__ __forceinline__ void ld16(V16h& o, const u16* p){
#pragma unroll
  for (int i = 0; i < 4; ++i) o.u2[i] = *(const uint2*)(p + 4 * i);
}

__device__ __forceinline__ float red16(float v){
  v += __shfl_xor(v, 1, 64);
  v += __shfl_xor(v, 2, 64);
  v += __shfl_xor(v, 4, 64);
  v += __shfl_xor(v, 8, 64);
  return v;
}

__global__ __launch_bounds__(192, 4)
void inter_encoder(Params p){
  __shared__ u16  sX[TOK * XS];
  __shared__ u16  sQKV[TOK * QS];   // cols 0..63 re-used as ATT after attention
  __shared__ float sRel[TOK];

  const int tid  = threadIdx.x;
  const int lane = tid & 63, wv = tid >> 6;     // wv in 0..2
  const int n15  = lane & 15, g = lane >> 4;    // g in 0..3
  const long long rowBase = (long long)blockIdx.x * ROWS_PB;

  // ---- stage X (f16) via float4, compute rel per token ----
#pragma unroll
  for (int it = 0; it < 4; ++it){
    int idx = it * 192 + tid;              // 768 float4 slots = [48][16]
    int t = idx >> 4, c4 = (idx & 15) * 4;
    int r = t / 3, m = t - 3 * r;
    const float* hp = (m == 0) ? p.h0 : (m == 1) ? p.h1 : p.h2;
    float4 vv = *(const float4*)(hp + (rowBase + r) * 64 + c4);
    u32 lo = (u32)f2h(vv.x) | ((u32)f2h(vv.y) << 16);
    u32 hi = (u32)f2h(vv.z) | ((u32)f2h(vv.w) << 16);
    *(uint2*)(sX + t * XS + c4) = make_uint2(lo, hi);
  }
  if (tid < TOK){
    int t = tid, r = t / 3, m = t - 3 * r;
    const float* mf = (m == 0) ? p.m0 : (m == 1) ? p.m1 : p.m2;
    float a0 = mf[(rowBase + r) * 2 + 0], a1 = mf[(rowBase + r) * 2 + 1];
    float z = a0 * p.relw[0] + a1 * p.relw[1] + p.relb[0];
    sRel[t] = 1.f / (1.f + __expf(-z));
  }
  __syncthreads();

  for (int l = 0; l < 2; ++l){
    const u16* wsl = p.ws + l * WS_L;

    // ---- GEMM1 (TRANSPOSED, the only change vs the validated kernel) ----
    // D[feat][tok]: A = Wqkv frag (wave wv owns feature m-tiles 4wv..4wv+3),
    // B = X^T frag read row-major from sX. D written back row-major
    // [token][feature] via one b64 store per (nt, j).
    Frag aq[4][2];
    v4f bq4[4];
#pragma unroll
    for (int j = 0; j < 4; ++j){
      int mt = 4 * wv + j;
      aq[j][0].u4 = *(const uint4*)(wsl + ((mt * 2 + 0) * 64 + lane) * 8);
      aq[j][1].u4 = *(const uint4*)(wsl + ((mt * 2 + 1) * 64 + lane) * 8);
      bq4[j] = *(const v4f*)(p.b_qkv[l] + 16 * mt + 4 * g);
    }
#pragma unroll
    for (int nt = 0; nt < 3; ++nt){
      const u16* bp = sX + (16 * nt + n15) * XS + 4 * g;
      v8h b0 = ldA(bp), b1 = ldA(bp + 32);
#pragma unroll
      for (int j = 0; j < 4; ++j){
        v4f acc = bq4[j];
        acc = __builtin_amdgcn_mfma_f32_16x16x32_f16(aq[j][0].v, b0, acc, 0, 0, 0);
        acc = __builtin_amdgcn_mfma_f32_16x16x32_f16(aq[j][1].v, b1, acc, 0, 0, 0);
        // thread holds QKV[16*(4wv+j)+4g+i][16nt+n15], i=0..3
        u32 lo = (u32)f2h(acc[0]) | ((u32)f2h(acc[1]) << 16);
        u32 hi = (u32)f2h(acc[2]) | ((u32)f2h(acc[3]) << 16);
        *(uint2*)(sQKV + (16 * nt + n15) * QS + 16 * (4 * wv + j) + 4 * g)
            = make_uint2(lo, hi);
      }
    }
    __syncthreads();

    // ---- attention: wave = query token t1, lane = (r, h) ----
    {
      const int t1 = wv, r = lane >> 2, h = lane & 3;
      const u16* base = sQKV + (3 * r) * QS + 16 * h;
      V16h q, k0, k1, k2;
      ld16(q,  base + t1 * QS);
      ld16(k0, base + 64);
      ld16(k1, base + QS + 64);
      ld16(k2, base + 2 * QS + 64);
      float s0 = 0.f, s1 = 0.f, s2 = 0.f;
#pragma unroll
      for (int pp = 0; pp < 8; ++pp){
        s0 = FDOT2(q.h[pp], k0.h[pp], s0);
        s1 = FDOT2(q.h[pp], k1.h[pp], s1);
        s2 = FDOT2(q.h[pp], k2.h[pp], s2);
      }
      s0 *= 0.25f; s1 *= 0.25f; s2 *= 0.25f;
      float mx = fmaxf(fmaxf(s0, s1), s2);
      float e0 = __expf(s0 - mx), e1 = __expf(s1 - mx), e2 = __expf(s2 - mx);
      float inv = 1.f / (e0 + e1 + e2);
      h16 w0 = (h16)(e0 * inv), w1 = (h16)(e1 * inv), w2 = (h16)(e2 * inv);
      h2v aw0 = {w0, w0}, aw1 = {w1, w1}, aw2 = {w2, w2};
      V16h v0, v1, v2, o;
      ld16(v0, base + 128);
      ld16(v1, base + QS + 128);
      ld16(v2, base + 2 * QS + 128);
#pragma unroll
      for (int pp = 0; pp < 8; ++pp)
        o.h[pp] = aw0 * v0.h[pp] + aw1 * v1.h[pp] + aw2 * v2.h[pp];
      u16* op = sQKV + (3 * r + t1) * QS + 16 * h;   // overwrite consumed Q region
#pragma unroll
      for (int pp = 0; pp < 4; ++pp) *(uint2*)(op + 4 * pp) = o.u2[pp];
    }
    __syncthreads();

    // ---- GEMM2 + LN1 (m-split: wave wv owns tokens 16wv..16wv+15) ----
    Frag bo[4][2];
    float biaso[4], g1v[4], b1v[4];
#pragma unroll
    for (int j = 0; j < 4; ++j){
#pragma unroll
      for (int kk = 0; kk < 2; ++kk)
        bo[j][kk].u4 = *(const uint4*)(wsl + 12288 + ((j * 2 + kk) * 64 + lane) * 8);
      biaso[j] = p.b_o[l][16 * j + n15];
      g1v[j] = p.n1g[l][16 * j + n15];
      b1v[j] = p.n1b[l][16 * j + n15];
    }
    {
      const u16* ap = sQKV + (16 * wv + n15) * QS + 4 * g;  // ATT rows, cols 0..63
      v8h a0 = ldA(ap), a1 = ldA(ap + 32);
      v4f acc[4];
#pragma unroll
      for (int j = 0; j < 4; ++j){
        acc[j] = (v4f){biaso[j], biaso[j], biaso[j], biaso[j]};
        acc[j] = __builtin_amdgcn_mfma_f32_16x16x32_f16(a0, bo[j][0].v, acc[j], 0, 0, 0);
        acc[j] = __builtin_amdgcn_mfma_f32_16x16x32_f16(a1, bo[j][1].v, acc[j], 0, 0, 0);
      }
#pragma unroll
      for (int i = 0; i < 4; ++i){
        int t = 16 * wv + 4 * g + i;
        float relt = sRel[t];
        float val[4], psum = 0.f;
#pragma unroll
        for (int j = 0; j < 4; ++j){
          val[j] = acc[j][i] * relt + h2f(sX[t * XS + 16 * j + n15]);
          psum += val[j];
        }
        float mu = red16(psum) * (1.f / 64.f);
        float dv[4], vs = 0.f;
#pragma unroll
        for (int j = 0; j < 4; ++j){ dv[j] = val[j] - mu; vs += dv[j] * dv[j]; }
        float rs = rsqrtf(red16(vs) * (1.f / 64.f) + 1e-5f);
#pragma unroll
        for (int j = 0; j < 4; ++j)
          sX[t * XS + 16 * j + n15] = f2h(dv[j] * rs * g1v[j] + b1v[j]);
      }
    }

    // ---- GEMM3 + LN2 (same wave ownership; no barrier needed in between) ----
    Frag bf[4][2];
    float biasf[4], g2v[4], b2v[4];
#pragma unroll
    for (int j = 0; j < 4; ++j){
#pragma unroll
      for (int kk = 0; kk < 2; ++kk)
        bf[j][kk].u4 = *(const uint4*)(wsl + 16384 + ((j * 2 + kk) * 64 + lane) * 8);
      biasf[j] = p.b_f[l][16 * j + n15];
      g2v[j] = p.n2g[l][16 * j + n15];
      b2v[j] = p.n2b[l][16 * j + n15];
    }
    {
      const u16* ap = sX + (16 * wv + n15) * XS + 4 * g;
      v8h a0 = ldA(ap), a1 = ldA(ap + 32);
      v4f acc[4];
#pragma unroll
      for (int j = 0; j < 4; ++j){
        acc[j] = (v4f){biasf[j], biasf[j], biasf[j], biasf[j]};
        acc[j] = __builtin_amdgcn_mfma_f32_16x16x32_f16(a0, bf[j][0].v, acc[j], 0, 0, 0);
        acc[j] = __builtin_amdgcn_mfma_f32_16x16x32_f16(a1, bf[j][1].v, acc[j], 0, 0, 0);
      }
#pragma unroll
      for (int i = 0; i < 4; ++i){
        int t = 16 * wv + 4 * g + i;
        float val[4], psum = 0.f;
#pragma unroll
        for (int j = 0; j < 4; ++j){
          val[j] = h2f(sX[t * XS + 16 * j + n15]) + fmaxf(acc[j][i], 0.f);
          psum += val[j];
        }
        float mu = red16(psum) * (1.f / 64.f);
        float dv[4], vs = 0.f;
#pragma unroll
        for (int j = 0; j < 4; ++j){ dv[j] = val[j] - mu; vs += dv[j] * dv[j]; }
        float rs = rsqrtf(red16(vs) * (1.f / 64.f) + 1e-5f);
#pragma unroll
        for (int j = 0; j < 4; ++j){
          float y = dv[j] * rs * g2v[j] + b2v[j];
          if (l == 0) sX[t * XS + 16 * j + n15] = f2h(y);
          else        p.out[(rowBase * 3 + t) * 64 + 16 * j + n15] = y;
        }
      }
    }
    __syncthreads();
  }
}

extern "C" void kernel_launch(void* const* d_in, const int* in_sizes, int n_in,
                              void* d_out, int out_size, void* d_ws, size_t ws_size,
                              hipStream_t stream){
  const float* const* in = (const float* const*)d_in;
  u16* ws = (u16*)d_ws;

  prep_w<<<(2 * WS_L + 255) / 256, 256, 0, stream>>>(
      in[8], in[10], in[12], in[18], in[20], in[22], ws);

  Params p;
  p.h0 = in[0]; p.h1 = in[1]; p.h2 = in[2];
  p.m0 = in[3]; p.m1 = in[4]; p.m2 = in[5];
  p.relw = in[6]; p.relb = in[7];
  for (int l = 0; l < 2; ++l){
    int b = 8 + 10 * l;
    p.b_qkv[l] = in[b + 1];
    p.b_o[l]   = in[b + 3];
    p.b_f[l]   = in[b + 5];
    p.n1g[l]   = in[b + 6]; p.n1b[l] = in[b + 7];
    p.n2g[l]   = in[b + 8]; p.n2b[l] = in[b + 9];
  }
  p.ws = ws;
  p.out = (float*)d_out;

  const int nblk = 524288 / ROWS_PB;  // 32768
  inter_encoder<<<nblk, 192, 0, stream>>>(p);
}

// Round 7
// 444.496 us; speedup vs baseline: 3.9442x; 1.0460x over previous
//
#include <hip/hip_runtime.h>

typedef unsigned short u16;
typedef unsigned int u32;
typedef _Float16 h16;
typedef h16 h2v __attribute__((ext_vector_type(2)));
typedef h16 v8h __attribute__((ext_vector_type(8)));
typedef float v4f __attribute__((ext_vector_type(4)));

#define ROWS_PB 16
#define TOK 48          // 3*ROWS_PB tokens per block
#define XS 76           // sX row stride (f16 elems)
#define QS 196          // sQKV row stride (f16 elems): 192 + 4 pad
#define WS_L 20480      // packed f16 weight elems per layer

struct Params {
  const float *h0, *h1, *h2;
  const float *m0, *m1, *m2;
  const float *relw, *relb;
  const float *b_qkv[2], *b_o[2], *b_f[2];
  const float *n1g[2], *n1b[2], *n2g[2], *n2b[2];
  const u16* ws;
  float* out;
};

__device__ __forceinline__ u16 f2h(float f){ union{h16 h; u16 u;} c; c.h = (h16)f; return c.u; }

union Frag { uint2 u2[2]; uint4 u4; v8h v; };
union V16h { uint2 u2[4]; h2v h[8]; h16 s[16]; };
union U2H  { uint2 u; h16 s[4]; };

#if __has_builtin(__builtin_amdgcn_fdot2)
#define FDOT2(a,b,c) __builtin_amdgcn_fdot2((a),(b),(c),false)
#else
#define FDOT2(a,b,c) ((float)(a)[0]*(float)(b)[0] + (float)(a)[1]*(float)(b)[1] + (c))
#endif

// Pack weights as f16 fragments (A and B maps are identical):
// lane l, elem e: m/n = tile*16 + (l&15); k = kk*32 + 4*(l>>4) + (e&3) + 16*(e>>2)
__global__ __launch_bounds__(256, 2)
void prep_w(const float* wq0, const float* wo0, const float* wf0,
            const float* wq1, const float* wo1, const float* wf1, u16* ws){
  int idx = blockIdx.x * 256 + threadIdx.x;
  if (idx >= 2 * WS_L) return;
  int l = idx / WS_L, rem = idx % WS_L;
  const float* W; int loc;
  if (rem < 12288)      { W = l ? wq1 : wq0; loc = rem; }          // w_qkv (192x64)
  else if (rem < 16384) { W = l ? wo1 : wo0; loc = rem - 12288; }  // w_o (64x64)
  else                  { W = l ? wf1 : wf0; loc = rem - 16384; }  // ffn_w (64x64)
  int e = loc & 7, lane = (loc >> 3) & 63, fk = loc >> 9;
  int kk = fk & 1, nt = fk >> 1;
  int k = kk * 32 + 4 * (lane >> 4) + (e & 3) + (e >> 2) * 16;
  int n = nt * 16 + (lane & 15);
  ws[idx] = f2h(W[n * 64 + k]);
}

__device__ __forceinline__ v8h ldA(const u16* ap){
  Frag f;
  f.u2[0] = *(const uint2*)(ap);
  f.u2[1] = *(const uint2*)(ap + 16);
  return f.v;
}
__device__ __forceinline__ void ld16(V16h& o, const u16* p){
#pragma unroll
  for (int i = 0; i < 4; ++i) o.u2[i] = *(const uint2*)(p + 4 * i);
}

__global__ __launch_bounds__(192, 4)
void inter_encoder(Params p){
  __shared__ u16  sX[TOK * XS];
  __shared__ u16  sQKV[TOK * QS];   // cols 0..63 re-used as ATT after attention
  __shared__ float sRel[TOK];

  const int tid  = threadIdx.x;
  const int lane = tid & 63, wv = tid >> 6;     // wv in 0..2
  const int n15  = lane & 15, g = lane >> 4;    // g in 0..3
  const long long rowBase = (long long)blockIdx.x * ROWS_PB;

  // ---- stage X (f16) via float4, compute rel per token ----
#pragma unroll
  for (int it = 0; it < 4; ++it){
    int idx = it * 192 + tid;              // 768 float4 slots = [48][16]
    int t = idx >> 4, c4 = (idx & 15) * 4;
    int r = t / 3, m = t - 3 * r;
    const float* hp = (m == 0) ? p.h0 : (m == 1) ? p.h1 : p.h2;
    float4 vv = *(const float4*)(hp + (rowBase + r) * 64 + c4);
    u32 lo = (u32)f2h(vv.x) | ((u32)f2h(vv.y) << 16);
    u32 hi = (u32)f2h(vv.z) | ((u32)f2h(vv.w) << 16);
    *(uint2*)(sX + t * XS + c4) = make_uint2(lo, hi);
  }
  if (tid < TOK){
    int t = tid, r = t / 3, m = t - 3 * r;
    const float* mf = (m == 0) ? p.m0 : (m == 1) ? p.m1 : p.m2;
    float a0 = mf[(rowBase + r) * 2 + 0], a1 = mf[(rowBase + r) * 2 + 1];
    float z = a0 * p.relw[0] + a1 * p.relw[1] + p.relb[0];
    sRel[t] = 1.f / (1.f + __expf(-z));
  }
  __syncthreads();

  for (int l = 0; l < 2; ++l){
    const u16* wsl = p.ws + l * WS_L;

    // ---- GEMM1 (transposed; validated in R6) ----
    Frag aq[4][2];
    v4f bq4[4];
#pragma unroll
    for (int j = 0; j < 4; ++j){
      int mt = 4 * wv + j;
      aq[j][0].u4 = *(const uint4*)(wsl + ((mt * 2 + 0) * 64 + lane) * 8);
      aq[j][1].u4 = *(const uint4*)(wsl + ((mt * 2 + 1) * 64 + lane) * 8);
      bq4[j] = *(const v4f*)(p.b_qkv[l] + 16 * mt + 4 * g);
    }
#pragma unroll
    for (int nt = 0; nt < 3; ++nt){
      const u16* bp = sX + (16 * nt + n15) * XS + 4 * g;
      v8h b0 = ldA(bp), b1 = ldA(bp + 32);
#pragma unroll
      for (int j = 0; j < 4; ++j){
        v4f acc = bq4[j];
        acc = __builtin_amdgcn_mfma_f32_16x16x32_f16(aq[j][0].v, b0, acc, 0, 0, 0);
        acc = __builtin_amdgcn_mfma_f32_16x16x32_f16(aq[j][1].v, b1, acc, 0, 0, 0);
        // thread holds QKV[16*(4wv+j)+4g+i][16nt+n15], i=0..3
        u32 lo = (u32)f2h(acc[0]) | ((u32)f2h(acc[1]) << 16);
        u32 hi = (u32)f2h(acc[2]) | ((u32)f2h(acc[3]) << 16);
        *(uint2*)(sQKV + (16 * nt + n15) * QS + 16 * (4 * wv + j) + 4 * g)
            = make_uint2(lo, hi);
      }
    }
    __syncthreads();

    // ---- attention: wave = query token t1, lane = (r, h) (validated) ----
    {
      const int t1 = wv, r = lane >> 2, h = lane & 3;
      const u16* base = sQKV + (3 * r) * QS + 16 * h;
      V16h q, k0, k1, k2;
      ld16(q,  base + t1 * QS);
      ld16(k0, base + 64);
      ld16(k1, base + QS + 64);
      ld16(k2, base + 2 * QS + 64);
      float s0 = 0.f, s1 = 0.f, s2 = 0.f;
#pragma unroll
      for (int pp = 0; pp < 8; ++pp){
        s0 = FDOT2(q.h[pp], k0.h[pp], s0);
        s1 = FDOT2(q.h[pp], k1.h[pp], s1);
        s2 = FDOT2(q.h[pp], k2.h[pp], s2);
      }
      s0 *= 0.25f; s1 *= 0.25f; s2 *= 0.25f;
      float mx = fmaxf(fmaxf(s0, s1), s2);
      float e0 = __expf(s0 - mx), e1 = __expf(s1 - mx), e2 = __expf(s2 - mx);
      float inv = 1.f / (e0 + e1 + e2);
      h16 w0 = (h16)(e0 * inv), w1 = (h16)(e1 * inv), w2 = (h16)(e2 * inv);
      h2v aw0 = {w0, w0}, aw1 = {w1, w1}, aw2 = {w2, w2};
      V16h v0, v1, v2, o;
      ld16(v0, base + 128);
      ld16(v1, base + QS + 128);
      ld16(v2, base + 2 * QS + 128);
#pragma unroll
      for (int pp = 0; pp < 8; ++pp)
        o.h[pp] = aw0 * v0.h[pp] + aw1 * v1.h[pp] + aw2 * v2.h[pp];
      u16* op = sQKV + (3 * r + t1) * QS + 16 * h;   // overwrite consumed Q region
#pragma unroll
      for (int pp = 0; pp < 4; ++pp) *(uint2*)(op + 4 * pp) = o.u2[pp];
    }
    __syncthreads();

    // ---- chain: G2^T + LN1 + G3^T + LN2, token-per-(wv,n15) ownership ----
    // D-map (validated by G1^T): thread (n15,g) holds feat 16j+4g+i of token
    // trow = 16wv+n15. LN reduces across g via shfl_xor 16/32. LN1 output is
    // written to sX as b64 and read back by the SAME thread as G3 B-frags
    // (own slice only -> same-wave DS ordering, no barrier needed).
    {
      const int trow = 16 * wv + n15;
      const float relt = sRel[trow];
      const u16* bp = sQKV + trow * QS + 4 * g;      // ATT^T B-frag (cols 0..63)
      v8h b0 = ldA(bp), b1 = ldA(bp + 32);

      float val[4][4];
      float psum = 0.f;
#pragma unroll
      for (int j = 0; j < 4; ++j){
        Frag a0, a1;
        a0.u4 = *(const uint4*)(wsl + 12288 + ((j * 2 + 0) * 64 + lane) * 8);
        a1.u4 = *(const uint4*)(wsl + 12288 + ((j * 2 + 1) * 64 + lane) * 8);
        v4f acc = *(const v4f*)(p.b_o[l] + 16 * j + 4 * g);
        acc = __builtin_amdgcn_mfma_f32_16x16x32_f16(a0.v, b0, acc, 0, 0, 0);
        acc = __builtin_amdgcn_mfma_f32_16x16x32_f16(a1.v, b1, acc, 0, 0, 0);
        U2H x; x.u = *(const uint2*)(sX + trow * XS + 16 * j + 4 * g);
#pragma unroll
        for (int i = 0; i < 4; ++i){
          val[j][i] = acc[i] * relt + (float)x.s[i];
          psum += val[j][i];
        }
      }
      psum += __shfl_xor(psum, 16, 64);
      psum += __shfl_xor(psum, 32, 64);
      float mu = psum * (1.f / 64.f);
      float vs = 0.f;
#pragma unroll
      for (int j = 0; j < 4; ++j)
#pragma unroll
        for (int i = 0; i < 4; ++i){ float d = val[j][i] - mu; vs += d * d; }
      vs += __shfl_xor(vs, 16, 64);
      vs += __shfl_xor(vs, 32, 64);
      float rs = rsqrtf(vs * (1.f / 64.f) + 1e-5f);

      float y[4][4];
#pragma unroll
      for (int j = 0; j < 4; ++j){
        v4f gg = *(const v4f*)(p.n1g[l] + 16 * j + 4 * g);
        v4f bb = *(const v4f*)(p.n1b[l] + 16 * j + 4 * g);
#pragma unroll
        for (int i = 0; i < 4; ++i) y[j][i] = (val[j][i] - mu) * rs * gg[i] + bb[i];
        u32 lo = (u32)f2h(y[j][0]) | ((u32)f2h(y[j][1]) << 16);
        u32 hi = (u32)f2h(y[j][2]) | ((u32)f2h(y[j][3]) << 16);
        *(uint2*)(sX + trow * XS + 16 * j + 4 * g) = make_uint2(lo, hi);
      }

      // G3^T: B-frags read back from sX (this thread's own slice)
      const u16* ap2 = sX + trow * XS + 4 * g;
      v8h c0 = ldA(ap2), c1 = ldA(ap2 + 32);

      float psum2 = 0.f;
#pragma unroll
      for (int j = 0; j < 4; ++j){
        Frag a0, a1;
        a0.u4 = *(const uint4*)(wsl + 16384 + ((j * 2 + 0) * 64 + lane) * 8);
        a1.u4 = *(const uint4*)(wsl + 16384 + ((j * 2 + 1) * 64 + lane) * 8);
        v4f acc = *(const v4f*)(p.b_f[l] + 16 * j + 4 * g);
        acc = __builtin_amdgcn_mfma_f32_16x16x32_f16(a0.v, c0, acc, 0, 0, 0);
        acc = __builtin_amdgcn_mfma_f32_16x16x32_f16(a1.v, c1, acc, 0, 0, 0);
#pragma unroll
        for (int i = 0; i < 4; ++i){
          float v2 = y[j][i] + fmaxf(acc[i], 0.f);   // residual from regs
          val[j][i] = v2;
          psum2 += v2;
        }
      }
      psum2 += __shfl_xor(psum2, 16, 64);
      psum2 += __shfl_xor(psum2, 32, 64);
      float mu2 = psum2 * (1.f / 64.f);
      float vs2 = 0.f;
#pragma unroll
      for (int j = 0; j < 4; ++j)
#pragma unroll
        for (int i = 0; i < 4; ++i){ float d = val[j][i] - mu2; vs2 += d * d; }
      vs2 += __shfl_xor(vs2, 16, 64);
      vs2 += __shfl_xor(vs2, 32, 64);
      float rs2 = rsqrtf(vs2 * (1.f / 64.f) + 1e-5f);

      if (l == 0){
#pragma unroll
        for (int j = 0; j < 4; ++j){
          v4f gg = *(const v4f*)(p.n2g[0] + 16 * j + 4 * g);
          v4f bb = *(const v4f*)(p.n2b[0] + 16 * j + 4 * g);
          float z0 = (val[j][0] - mu2) * rs2 * gg[0] + bb[0];
          float z1 = (val[j][1] - mu2) * rs2 * gg[1] + bb[1];
          float z2 = (val[j][2] - mu2) * rs2 * gg[2] + bb[2];
          float z3 = (val[j][3] - mu2) * rs2 * gg[3] + bb[3];
          u32 lo = (u32)f2h(z0) | ((u32)f2h(z1) << 16);
          u32 hi = (u32)f2h(z2) | ((u32)f2h(z3) << 16);
          *(uint2*)(sX + trow * XS + 16 * j + 4 * g) = make_uint2(lo, hi);
        }
      } else {
        float* op = p.out + (rowBase * 3 + trow) * 64;
#pragma unroll
        for (int j = 0; j < 4; ++j){
          v4f gg = *(const v4f*)(p.n2g[1] + 16 * j + 4 * g);
          v4f bb = *(const v4f*)(p.n2b[1] + 16 * j + 4 * g);
          v4f yo;
#pragma unroll
          for (int i = 0; i < 4; ++i) yo[i] = (val[j][i] - mu2) * rs2 * gg[i] + bb[i];
          *(v4f*)(op + 16 * j + 4 * g) = yo;
        }
      }
    }
    __syncthreads();
  }
}

extern "C" void kernel_launch(void* const* d_in, const int* in_sizes, int n_in,
                              void* d_out, int out_size, void* d_ws, size_t ws_size,
                              hipStream_t stream){
  const float* const* in = (const float* const*)d_in;
  u16* ws = (u16*)d_ws;

  prep_w<<<(2 * WS_L + 255) / 256, 256, 0, stream>>>(
      in[8], in[10], in[12], in[18], in[20], in[22], ws);

  Params p;
  p.h0 = in[0]; p.h1 = in[1]; p.h2 = in[2];
  p.m0 = in[3]; p.m1 = in[4]; p.m2 = in[5];
  p.relw = in[6]; p.relb = in[7];
  for (int l = 0; l < 2; ++l){
    int b = 8 + 10 * l;
    p.b_qkv[l] = in[b + 1];
    p.b_o[l]   = in[b + 3];
    p.b_f[l]   = in[b + 5];
    p.n1g[l]   = in[b + 6]; p.n1b[l] = in[b + 7];
    p.n2g[l]   = in[b + 8]; p.n2b[l] = in[b + 9];
  }
  p.ws = ws;
  p.out = (float*)d_out;

  const int nblk = 524288 / ROWS_PB;  // 32768
  inter_encoder<<<nblk, 192, 0, stream>>>(p);
}